// Round 5
// baseline (317.874 us; speedup 1.0000x reference)
//
#include <hip/hip_runtime.h>

// FFF tree traversal, round 4b (compile fix): fused single kernel with BOTH
// weight matrices in bf16 to halve the L3-bandwidth-bound weight stream
// (2.88 GB -> 1.48 GB). Sign safety: if |bf16 score| < EPS (~0.8% of
// row-levels), recompute that dot from fp32 w1 (wave-uniform rare branch).
// y stores plain (nt stores doubled WRITE_SIZE in round 2). x loads nt.

typedef float          f32x4 __attribute__((ext_vector_type(4)));
typedef unsigned short u16x4 __attribute__((ext_vector_type(4)));
typedef unsigned short u16x8 __attribute__((ext_vector_type(8)));

#define FFF_BATCH  32768
#define FFF_NIN    1024
#define FFF_NOUT   1024
#define FFF_LEVELS 11
#define FFF_NODES  2047
#define FFF_EPS    0.01f

__device__ __forceinline__ f32x4 ld_nt4f(const f32x4* p) { return __builtin_nontemporal_load(p); }
__device__ __forceinline__ float upbf(unsigned short u) { return __uint_as_float((unsigned)u << 16); }

// ---- prep: fp32 -> bf16 (RNE). Blocks 0..2046 convert w1, 2047..4093 w2. ----
__global__ void fff_to_bf16(const float* __restrict__ w1, const float* __restrict__ w2,
                            unsigned short* __restrict__ o1, unsigned short* __restrict__ o2)
{
    const bool second = blockIdx.x >= FFF_NODES;
    const int  blk    = second ? (blockIdx.x - FFF_NODES) : blockIdx.x;
    const int  i      = blk * blockDim.x + threadIdx.x;       // one float4 / thread
    const float* src  = second ? w2 : w1;
    unsigned short* dst = second ? o2 : o1;

    const f32x4 v = reinterpret_cast<const f32x4*>(src)[i];
    u16x4 u;
#pragma unroll
    for (int k = 0; k < 4; ++k) {
        unsigned b = __float_as_uint(v[k]);
        b = (b + 0x7FFFu + ((b >> 16) & 1u)) >> 16;            // round-to-nearest-even
        u[k] = (unsigned short)b;
    }
    reinterpret_cast<u16x4*>(dst)[i] = u;
}

// ---- main fused kernel: 2 rows per wave, 4 waves per block ----
__global__ __launch_bounds__(256, 4) void fff_main_bf16(
    const float*          __restrict__ x,
    const unsigned short* __restrict__ w1b,
    const float*          __restrict__ w1f,   // fp32 w1 for the EPS fallback
    const unsigned short* __restrict__ w2b,
    float*                __restrict__ y)
{
    const int wave = threadIdx.x >> 6;
    const int lane = threadIdx.x & 63;
    const int row0 = (blockIdx.x * 4 + wave) * 2;

    // x layout: lane owns elems lane*8..+7 and 512+lane*8..+7
    // (f32x4 indices lane*2, lane*2+1, 128+lane*2, 128+lane*2+1)
    f32x4 xv[2][4];
#pragma unroll
    for (int r = 0; r < 2; ++r) {
        const f32x4* x4 = reinterpret_cast<const f32x4*>(x + (size_t)(row0 + r) * FFF_NIN);
        xv[r][0] = ld_nt4f(&x4[lane * 2]);
        xv[r][1] = ld_nt4f(&x4[lane * 2 + 1]);
        xv[r][2] = ld_nt4f(&x4[128 + lane * 2]);
        xv[r][3] = ld_nt4f(&x4[128 + lane * 2 + 1]);
    }

    f32x4 acc[2][4];
#pragma unroll
    for (int r = 0; r < 2; ++r)
#pragma unroll
        for (int c = 0; c < 4; ++c) acc[r][c] = (f32x4)(0.f);

    int node[2] = {0, 0};

#pragma unroll
    for (int l = 0; l < FFF_LEVELS; ++l) {
        // ---- bf16 w1 fragments (2 x 16B per lane per row) ----
        u16x8 a0[2], a1[2];
#pragma unroll
        for (int r = 0; r < 2; ++r) {
            const u16x8* w1r = reinterpret_cast<const u16x8*>(w1b + (size_t)node[r] * FFF_NIN);
            a0[r] = w1r[lane];
            a1[r] = w1r[64 + lane];
        }
        // ---- bf16 w2 fragments issued early (latency under reduce) ----
        u16x8 b0[2], b1[2];
#pragma unroll
        for (int r = 0; r < 2; ++r) {
            const u16x8* w2r = reinterpret_cast<const u16x8*>(w2b + (size_t)node[r] * FFF_NOUT);
            b0[r] = w2r[lane];
            b1[r] = w2r[64 + lane];
        }

        // ---- dots ----
        float p[2];
#pragma unroll
        for (int r = 0; r < 2; ++r) {
            float s = 0.f;
#pragma unroll
            for (int k = 0; k < 4; ++k) {
                s = fmaf(xv[r][0][k], upbf(a0[r][k]),     s);
                s = fmaf(xv[r][1][k], upbf(a0[r][4 + k]), s);
                s = fmaf(xv[r][2][k], upbf(a1[r][k]),     s);
                s = fmaf(xv[r][3][k], upbf(a1[r][4 + k]), s);
            }
            p[r] = s;
        }

        // ---- interleaved butterfly reduce ----
#pragma unroll
        for (int m = 1; m < 64; m <<= 1) {
            const float t0 = __shfl_xor(p[0], m, 64);
            const float t1 = __shfl_xor(p[1], m, 64);
            p[0] += t0; p[1] += t1;
        }

        // ---- rare wave-uniform fp32 recompute for near-zero scores ----
#pragma unroll
        for (int r = 0; r < 2; ++r) {
            if (__builtin_expect(fabsf(p[r]) < FFF_EPS, 0)) {
                const f32x4* w14 = reinterpret_cast<const f32x4*>(w1f + (size_t)node[r] * FFF_NIN);
                const f32x4 w0  = w14[lane * 2];
                const f32x4 w1_ = w14[lane * 2 + 1];
                const f32x4 w2_ = w14[128 + lane * 2];
                const f32x4 w3  = w14[128 + lane * 2 + 1];
                float s = 0.f;
#pragma unroll
                for (int k = 0; k < 4; ++k) {
                    s = fmaf(xv[r][0][k], w0[k], s);
                    s = fmaf(xv[r][1][k], w1_[k], s);
                    s = fmaf(xv[r][2][k], w2_[k], s);
                    s = fmaf(xv[r][3][k], w3[k], s);
                }
#pragma unroll
                for (int m = 1; m < 64; m <<= 1) s += __shfl_xor(s, m, 64);
                p[r] = s;
            }
        }

        // ---- accumulate y, advance nodes ----
#pragma unroll
        for (int r = 0; r < 2; ++r) {
            const float score = p[r];
#pragma unroll
            for (int k = 0; k < 4; ++k) {
                acc[r][0][k] = fmaf(score, upbf(b0[r][k]),     acc[r][0][k]);
                acc[r][1][k] = fmaf(score, upbf(b0[r][4 + k]), acc[r][1][k]);
                acc[r][2][k] = fmaf(score, upbf(b1[r][k]),     acc[r][2][k]);
                acc[r][3][k] = fmaf(score, upbf(b1[r][4 + k]), acc[r][3][k]);
            }
            node[r] = node[r] * 2 + 1 + ((score > 0.f) ? 1 : 0);
        }
    }

    // ---- plain coalesced y stores ----
#pragma unroll
    for (int r = 0; r < 2; ++r) {
        f32x4* y4 = reinterpret_cast<f32x4*>(y + (size_t)(row0 + r) * FFF_NOUT);
        y4[lane * 2]           = acc[r][0];
        y4[lane * 2 + 1]       = acc[r][1];
        y4[128 + lane * 2]     = acc[r][2];
        y4[128 + lane * 2 + 1] = acc[r][3];
    }
}

// ---- safety fallback: proven round-1 fp32 fused kernel ----
__global__ __launch_bounds__(256, 4) void fff_fused_f32(
    const float* __restrict__ x, const float* __restrict__ w1s,
    const float* __restrict__ w2s, float* __restrict__ y)
{
    const int row  = blockIdx.x * 4 + (threadIdx.x >> 6);
    const int lane = threadIdx.x & 63;
    const f32x4* x4 = reinterpret_cast<const f32x4*>(x + (size_t)row * FFF_NIN);
    f32x4 xv[4];
#pragma unroll
    for (int c = 0; c < 4; ++c) xv[c] = x4[c * 64 + lane];
    f32x4 acc[4];
#pragma unroll
    for (int c = 0; c < 4; ++c) acc[c] = (f32x4)(0.f);
    int node = 0;
#pragma unroll
    for (int l = 0; l < FFF_LEVELS; ++l) {
        const f32x4* w14 = reinterpret_cast<const f32x4*>(w1s + (size_t)node * FFF_NIN);
        const f32x4* w24 = reinterpret_cast<const f32x4*>(w2s + (size_t)node * FFF_NOUT);
        f32x4 wv[4], uv[4];
#pragma unroll
        for (int c = 0; c < 4; ++c) { wv[c] = w14[c * 64 + lane]; uv[c] = w24[c * 64 + lane]; }
        float p = 0.f;
#pragma unroll
        for (int c = 0; c < 4; ++c) {
            p = fmaf(xv[c][0], wv[c][0], p); p = fmaf(xv[c][1], wv[c][1], p);
            p = fmaf(xv[c][2], wv[c][2], p); p = fmaf(xv[c][3], wv[c][3], p);
        }
#pragma unroll
        for (int m = 1; m < 64; m <<= 1) p += __shfl_xor(p, m, 64);
#pragma unroll
        for (int c = 0; c < 4; ++c) {
            acc[c][0] = fmaf(p, uv[c][0], acc[c][0]); acc[c][1] = fmaf(p, uv[c][1], acc[c][1]);
            acc[c][2] = fmaf(p, uv[c][2], acc[c][2]); acc[c][3] = fmaf(p, uv[c][3], acc[c][3]);
        }
        node = node * 2 + 1 + ((p > 0.f) ? 1 : 0);
    }
    f32x4* y4 = reinterpret_cast<f32x4*>(y + (size_t)row * FFF_NOUT);
#pragma unroll
    for (int c = 0; c < 4; ++c) y4[c * 64 + lane] = acc[c];
}

extern "C" void kernel_launch(void* const* d_in, const int* in_sizes, int n_in,
                              void* d_out, int out_size, void* d_ws, size_t ws_size,
                              hipStream_t stream) {
    const float* x   = (const float*)d_in[0];
    const float* w1s = (const float*)d_in[1];
    const float* w2s = (const float*)d_in[2];
    float* y = (float*)d_out;

    const size_t wb_bytes = (size_t)FFF_NODES * FFF_NIN * sizeof(unsigned short); // 4,192,256
    const size_t need = 2 * wb_bytes;                                             // 8,384,512

    if (ws_size >= need) {
        unsigned short* w1b = (unsigned short*)d_ws;
        unsigned short* w2b = (unsigned short*)((char*)d_ws + wb_bytes);
        fff_to_bf16<<<2 * FFF_NODES, 256, 0, stream>>>(w1s, w2s, w1b, w2b);
        fff_main_bf16<<<FFF_BATCH / 8, 256, 0, stream>>>(x, w1b, w1s, w2b, y);
    } else {
        fff_fused_f32<<<FFF_BATCH / 4, 256, 0, stream>>>(x, w1s, w2s, y);
    }
}

// Round 6
// 309.138 us; speedup vs baseline: 1.0283x; 1.0283x over previous
//
#include <hip/hip_runtime.h>

// FFF tree traversal, round 6: bf16 weights (halve the L3-bound weight
// stream) + PERMUTED weight storage so every global access is a fully
// coalesced 16B/lane transaction under the round-1 x/y layout.
//
// Layouts:
//   x/y   : lane owns f32x4 at index c*64+lane  (elements 256c+4*lane..+3)
//   w1p/w2p (packed bf16, per node 128 u16x8 slots): slot s = half*64+lane
//           holds source elems {512*half+4*lane+k} (k<4 half of slot) and
//           {512*half+256+4*lane+k} (k>=4 half) -> slot read by lane pairs
//           exactly with that lane's xv/acc fragments.
// Sign safety: |score| < EPS -> recompute dot in fp32 (wave-uniform, rare).

typedef float          f32x4 __attribute__((ext_vector_type(4)));
typedef unsigned short u16x8 __attribute__((ext_vector_type(8)));

#define FFF_BATCH  32768
#define FFF_NIN    1024
#define FFF_NOUT   1024
#define FFF_LEVELS 11
#define FFF_NODES  2047
#define FFF_EPS    0.01f
#define SLOTS      (FFF_NODES * 128)   // u16x8 slots per packed matrix

__device__ __forceinline__ f32x4 ld_nt4f(const f32x4* p) { return __builtin_nontemporal_load(p); }
__device__ __forceinline__ float upbf(unsigned short u) { return __uint_as_float((unsigned)u << 16); }
__device__ __forceinline__ unsigned short tobf(float f) {
    unsigned b = __float_as_uint(f);
    b = (b + 0x7FFFu + ((b >> 16) & 1u)) >> 16;   // round-to-nearest-even
    return (unsigned short)b;
}

// ---- prep: fp32 -> bf16 with the fragment permutation baked in ----
// One thread per output u16x8 slot. Threads [0,SLOTS) pack w1, rest pack w2.
// Grid: 2*SLOTS/256 = 2047 blocks exactly.
__global__ void fff_pack_bf16(const float* __restrict__ w1, const float* __restrict__ w2,
                              u16x8* __restrict__ o1, u16x8* __restrict__ o2)
{
    int t = blockIdx.x * blockDim.x + threadIdx.x;
    const bool second = t >= SLOTS;
    if (second) t -= SLOTS;
    const float* src = second ? w2 : w1;
    u16x8*       dst = second ? o2 : o1;

    const int node = t >> 7;
    const int s    = t & 127;
    const int half = s >> 6;
    const int lane = s & 63;

    const f32x4* sp = reinterpret_cast<const f32x4*>(src + (size_t)node * FFF_NIN);
    const f32x4 lo = sp[half * 128 + lane];        // elems 512*half + 4*lane ..+3
    const f32x4 hi = sp[half * 128 + 64 + lane];   // elems 512*half + 256 + 4*lane ..+3

    u16x8 o;
#pragma unroll
    for (int k = 0; k < 4; ++k) { o[k] = tobf(lo[k]); o[4 + k] = tobf(hi[k]); }
    dst[t] = o;
}

// ---- main fused kernel: 2 rows per wave, 4 waves per block ----
__global__ __launch_bounds__(256, 4) void fff_main_bf16(
    const float* __restrict__ x,
    const u16x8* __restrict__ w1p,
    const float* __restrict__ w1f,   // fp32 w1 for the EPS fallback
    const u16x8* __restrict__ w2p,
    float*       __restrict__ y)
{
    const int wave = threadIdx.x >> 6;
    const int lane = threadIdx.x & 63;
    const int row0 = (blockIdx.x * 4 + wave) * 2;

    // round-1 coalesced x layout: xv[c] = elements 256c + 4*lane ..+3
    f32x4 xv[2][4];
#pragma unroll
    for (int r = 0; r < 2; ++r) {
        const f32x4* x4 = reinterpret_cast<const f32x4*>(x + (size_t)(row0 + r) * FFF_NIN);
#pragma unroll
        for (int c = 0; c < 4; ++c) xv[r][c] = ld_nt4f(&x4[c * 64 + lane]);
    }

    f32x4 acc[2][4];
#pragma unroll
    for (int r = 0; r < 2; ++r)
#pragma unroll
        for (int c = 0; c < 4; ++c) acc[r][c] = (f32x4)(0.f);

    int node[2] = {0, 0};

#pragma unroll
    for (int l = 0; l < FFF_LEVELS; ++l) {
        // packed-bf16 fragments: 16B/lane, fully coalesced
        u16x8 a0[2], a1[2], b0[2], b1[2];
#pragma unroll
        for (int r = 0; r < 2; ++r) {
            const u16x8* w1r = w1p + (size_t)node[r] * 128;
            a0[r] = w1r[lane];
            a1[r] = w1r[64 + lane];
            const u16x8* w2r = w2p + (size_t)node[r] * 128;
            b0[r] = w2r[lane];
            b1[r] = w2r[64 + lane];
        }

        // dots: slot halves pair with xv[0..3] by construction
        float p[2];
#pragma unroll
        for (int r = 0; r < 2; ++r) {
            float s = 0.f;
#pragma unroll
            for (int k = 0; k < 4; ++k) {
                s = fmaf(xv[r][0][k], upbf(a0[r][k]),     s);
                s = fmaf(xv[r][1][k], upbf(a0[r][4 + k]), s);
                s = fmaf(xv[r][2][k], upbf(a1[r][k]),     s);
                s = fmaf(xv[r][3][k], upbf(a1[r][4 + k]), s);
            }
            p[r] = s;
        }

        // interleaved butterfly reduce
#pragma unroll
        for (int m = 1; m < 64; m <<= 1) {
            const float t0 = __shfl_xor(p[0], m, 64);
            const float t1 = __shfl_xor(p[1], m, 64);
            p[0] += t0; p[1] += t1;
        }

        // rare wave-uniform fp32 recompute for near-zero scores
#pragma unroll
        for (int r = 0; r < 2; ++r) {
            if (__builtin_expect(fabsf(p[r]) < FFF_EPS, 0)) {
                const f32x4* w14 = reinterpret_cast<const f32x4*>(w1f + (size_t)node[r] * FFF_NIN);
                float s = 0.f;
#pragma unroll
                for (int c = 0; c < 4; ++c) {
                    const f32x4 w = w14[c * 64 + lane];
                    s = fmaf(xv[r][c][0], w[0], s);
                    s = fmaf(xv[r][c][1], w[1], s);
                    s = fmaf(xv[r][c][2], w[2], s);
                    s = fmaf(xv[r][c][3], w[3], s);
                }
#pragma unroll
                for (int m = 1; m < 64; m <<= 1) s += __shfl_xor(s, m, 64);
                p[r] = s;
            }
        }

        // accumulate y, advance nodes
#pragma unroll
        for (int r = 0; r < 2; ++r) {
            const float score = p[r];
#pragma unroll
            for (int k = 0; k < 4; ++k) {
                acc[r][0][k] = fmaf(score, upbf(b0[r][k]),     acc[r][0][k]);
                acc[r][1][k] = fmaf(score, upbf(b0[r][4 + k]), acc[r][1][k]);
                acc[r][2][k] = fmaf(score, upbf(b1[r][k]),     acc[r][2][k]);
                acc[r][3][k] = fmaf(score, upbf(b1[r][4 + k]), acc[r][3][k]);
            }
            node[r] = node[r] * 2 + 1 + ((score > 0.f) ? 1 : 0);
        }
    }

    // round-1 coalesced y stores
#pragma unroll
    for (int r = 0; r < 2; ++r) {
        f32x4* y4 = reinterpret_cast<f32x4*>(y + (size_t)(row0 + r) * FFF_NOUT);
#pragma unroll
        for (int c = 0; c < 4; ++c) y4[c * 64 + lane] = acc[r][c];
    }
}

// ---- safety fallback: proven round-1 fp32 fused kernel ----
__global__ __launch_bounds__(256, 4) void fff_fused_f32(
    const float* __restrict__ x, const float* __restrict__ w1s,
    const float* __restrict__ w2s, float* __restrict__ y)
{
    const int row  = blockIdx.x * 4 + (threadIdx.x >> 6);
    const int lane = threadIdx.x & 63;
    const f32x4* x4 = reinterpret_cast<const f32x4*>(x + (size_t)row * FFF_NIN);
    f32x4 xv[4];
#pragma unroll
    for (int c = 0; c < 4; ++c) xv[c] = x4[c * 64 + lane];
    f32x4 acc[4];
#pragma unroll
    for (int c = 0; c < 4; ++c) acc[c] = (f32x4)(0.f);
    int node = 0;
#pragma unroll
    for (int l = 0; l < FFF_LEVELS; ++l) {
        const f32x4* w14 = reinterpret_cast<const f32x4*>(w1s + (size_t)node * FFF_NIN);
        const f32x4* w24 = reinterpret_cast<const f32x4*>(w2s + (size_t)node * FFF_NOUT);
        f32x4 wv[4], uv[4];
#pragma unroll
        for (int c = 0; c < 4; ++c) { wv[c] = w14[c * 64 + lane]; uv[c] = w24[c * 64 + lane]; }
        float p = 0.f;
#pragma unroll
        for (int c = 0; c < 4; ++c) {
            p = fmaf(xv[c][0], wv[c][0], p); p = fmaf(xv[c][1], wv[c][1], p);
            p = fmaf(xv[c][2], wv[c][2], p); p = fmaf(xv[c][3], wv[c][3], p);
        }
#pragma unroll
        for (int m = 1; m < 64; m <<= 1) p += __shfl_xor(p, m, 64);
#pragma unroll
        for (int c = 0; c < 4; ++c) {
            acc[c][0] = fmaf(p, uv[c][0], acc[c][0]); acc[c][1] = fmaf(p, uv[c][1], acc[c][1]);
            acc[c][2] = fmaf(p, uv[c][2], acc[c][2]); acc[c][3] = fmaf(p, uv[c][3], acc[c][3]);
        }
        node = node * 2 + 1 + ((p > 0.f) ? 1 : 0);
    }
    f32x4* y4 = reinterpret_cast<f32x4*>(y + (size_t)row * FFF_NOUT);
#pragma unroll
    for (int c = 0; c < 4; ++c) y4[c * 64 + lane] = acc[c];
}

extern "C" void kernel_launch(void* const* d_in, const int* in_sizes, int n_in,
                              void* d_out, int out_size, void* d_ws, size_t ws_size,
                              hipStream_t stream) {
    const float* x   = (const float*)d_in[0];
    const float* w1s = (const float*)d_in[1];
    const float* w2s = (const float*)d_in[2];
    float* y = (float*)d_out;

    const size_t wb_bytes = (size_t)SLOTS * sizeof(u16x8);   // 4,192,256
    const size_t need = 2 * wb_bytes;                        // 8,384,512

    if (ws_size >= need) {
        u16x8* w1p = (u16x8*)d_ws;
        u16x8* w2p = (u16x8*)((char*)d_ws + wb_bytes);
        // 2*SLOTS = 524032 threads = 2047 blocks * 256 exactly
        fff_pack_bf16<<<2 * SLOTS / 256, 256, 0, stream>>>(w1s, w2s, w1p, w2p);
        fff_main_bf16<<<FFF_BATCH / 8, 256, 0, stream>>>(x, w1p, w1s, w2p, y);
    } else {
        fff_fused_f32<<<FFF_BATCH / 4, 256, 0, stream>>>(x, w1s, w2s, y);
    }
}

// Round 7
// 148.280 us; speedup vs baseline: 2.1437x; 2.0848x over previous
//
#include <hip/hip_runtime.h>

// FFF tree traversal, round 7: round-1 single-row-per-wave structure (44
// VGPR, no spills — rounds 2/5/6's 2-row variants spilled to scratch:
// VGPR_Count=64 vs >=110 live, WRITE_SIZE 131->776 MiB was spill traffic)
// + bf16 packed weights (halves the L3-bound weight stream 2.88->1.48 GB).
//
// Layouts:
//   x/y : lane owns f32x4 at index c*64+lane (elements 256c+4*lane..+3)
//   w1p/w2p (packed bf16, 128 u16x8 slots/node): slot s=half*64+lane holds
//     elems {512*half+4*lane+k} (k<4) and {512*half+256+4*lane+k} (k>=4),
//     so slot halves pair exactly with that lane's xv/acc fragments.
// Sign safety: |score| < EPS -> recompute dot in fp32 (wave-uniform, rare).

typedef float          f32x4 __attribute__((ext_vector_type(4)));
typedef unsigned short u16x8 __attribute__((ext_vector_type(8)));

#define FFF_BATCH  32768
#define FFF_NIN    1024
#define FFF_NOUT   1024
#define FFF_LEVELS 11
#define FFF_NODES  2047
#define FFF_EPS    0.01f
#define SLOTS      (FFF_NODES * 128)   // u16x8 slots per packed matrix

__device__ __forceinline__ f32x4 ld_nt4f(const f32x4* p) { return __builtin_nontemporal_load(p); }
__device__ __forceinline__ float upbf(unsigned short u) { return __uint_as_float((unsigned)u << 16); }
__device__ __forceinline__ unsigned short tobf(float f) {
    unsigned b = __float_as_uint(f);
    b = (b + 0x7FFFu + ((b >> 16) & 1u)) >> 16;   // round-to-nearest-even
    return (unsigned short)b;
}

// ---- prep: fp32 -> bf16 with the fragment permutation baked in ----
__global__ void fff_pack_bf16(const float* __restrict__ w1, const float* __restrict__ w2,
                              u16x8* __restrict__ o1, u16x8* __restrict__ o2)
{
    int t = blockIdx.x * blockDim.x + threadIdx.x;
    const bool second = t >= SLOTS;
    if (second) t -= SLOTS;
    const float* src = second ? w2 : w1;
    u16x8*       dst = second ? o2 : o1;

    const int node = t >> 7;
    const int s    = t & 127;
    const int half = s >> 6;
    const int lane = s & 63;

    const f32x4* sp = reinterpret_cast<const f32x4*>(src + (size_t)node * FFF_NIN);
    const f32x4 lo = sp[half * 128 + lane];        // elems 512*half + 4*lane ..+3
    const f32x4 hi = sp[half * 128 + 64 + lane];   // elems 512*half + 256 + 4*lane ..+3

    u16x8 o;
#pragma unroll
    for (int k = 0; k < 4; ++k) { o[k] = tobf(lo[k]); o[4 + k] = tobf(hi[k]); }
    dst[t] = o;
}

// ---- main fused kernel: ONE row per wave (no spill), 4 waves/block ----
__global__ __launch_bounds__(256, 4) void fff_main_bf16(
    const float* __restrict__ x,
    const u16x8* __restrict__ w1p,
    const float* __restrict__ w1f,   // fp32 w1 for the EPS fallback
    const u16x8* __restrict__ w2p,
    float*       __restrict__ y)
{
    const int row  = blockIdx.x * 4 + (threadIdx.x >> 6);
    const int lane = threadIdx.x & 63;

    // coalesced x: xv[c] = elements 256c + 4*lane ..+3
    const f32x4* x4 = reinterpret_cast<const f32x4*>(x + (size_t)row * FFF_NIN);
    f32x4 xv[4];
#pragma unroll
    for (int c = 0; c < 4; ++c) xv[c] = ld_nt4f(&x4[c * 64 + lane]);

    f32x4 acc[4];
#pragma unroll
    for (int c = 0; c < 4; ++c) acc[c] = (f32x4)(0.f);

    int node = 0;

#pragma unroll
    for (int l = 0; l < FFF_LEVELS; ++l) {
        const u16x8* w1r = w1p + (size_t)node * 128;
        const u16x8  a0  = w1r[lane];
        const u16x8  a1  = w1r[64 + lane];
        const u16x8* w2r = w2p + (size_t)node * 128;
        const u16x8  b0  = w2r[lane];
        const u16x8  b1  = w2r[64 + lane];

        // dot: slot halves pair with xv[0..3] by construction
        float p = 0.f;
#pragma unroll
        for (int k = 0; k < 4; ++k) {
            p = fmaf(xv[0][k], upbf(a0[k]),     p);
            p = fmaf(xv[1][k], upbf(a0[4 + k]), p);
            p = fmaf(xv[2][k], upbf(a1[k]),     p);
            p = fmaf(xv[3][k], upbf(a1[4 + k]), p);
        }

        // 64-lane butterfly reduce
#pragma unroll
        for (int m = 1; m < 64; m <<= 1) p += __shfl_xor(p, m, 64);

        // rare wave-uniform fp32 recompute for near-zero scores
        if (__builtin_expect(fabsf(p) < FFF_EPS, 0)) {
            const f32x4* w14 = reinterpret_cast<const f32x4*>(w1f + (size_t)node * FFF_NIN);
            float s = 0.f;
#pragma unroll
            for (int c = 0; c < 4; ++c) {
                const f32x4 w = w14[c * 64 + lane];
                s = fmaf(xv[c][0], w[0], s);
                s = fmaf(xv[c][1], w[1], s);
                s = fmaf(xv[c][2], w[2], s);
                s = fmaf(xv[c][3], w[3], s);
            }
#pragma unroll
            for (int m = 1; m < 64; m <<= 1) s += __shfl_xor(s, m, 64);
            p = s;
        }

        // accumulate y, advance node
#pragma unroll
        for (int k = 0; k < 4; ++k) {
            acc[0][k] = fmaf(p, upbf(b0[k]),     acc[0][k]);
            acc[1][k] = fmaf(p, upbf(b0[4 + k]), acc[1][k]);
            acc[2][k] = fmaf(p, upbf(b1[k]),     acc[2][k]);
            acc[3][k] = fmaf(p, upbf(b1[4 + k]), acc[3][k]);
        }
        node = node * 2 + 1 + ((p > 0.f) ? 1 : 0);
    }

    // coalesced y stores (full 128B lines per wave instruction)
    f32x4* y4 = reinterpret_cast<f32x4*>(y + (size_t)row * FFF_NOUT);
#pragma unroll
    for (int c = 0; c < 4; ++c) y4[c * 64 + lane] = acc[c];
}

// ---- safety fallback: proven round-1 fp32 fused kernel ----
__global__ __launch_bounds__(256, 4) void fff_fused_f32(
    const float* __restrict__ x, const float* __restrict__ w1s,
    const float* __restrict__ w2s, float* __restrict__ y)
{
    const int row  = blockIdx.x * 4 + (threadIdx.x >> 6);
    const int lane = threadIdx.x & 63;
    const f32x4* x4 = reinterpret_cast<const f32x4*>(x + (size_t)row * FFF_NIN);
    f32x4 xv[4];
#pragma unroll
    for (int c = 0; c < 4; ++c) xv[c] = x4[c * 64 + lane];
    f32x4 acc[4];
#pragma unroll
    for (int c = 0; c < 4; ++c) acc[c] = (f32x4)(0.f);
    int node = 0;
#pragma unroll
    for (int l = 0; l < FFF_LEVELS; ++l) {
        const f32x4* w14 = reinterpret_cast<const f32x4*>(w1s + (size_t)node * FFF_NIN);
        const f32x4* w24 = reinterpret_cast<const f32x4*>(w2s + (size_t)node * FFF_NOUT);
        f32x4 wv[4], uv[4];
#pragma unroll
        for (int c = 0; c < 4; ++c) { wv[c] = w14[c * 64 + lane]; uv[c] = w24[c * 64 + lane]; }
        float p = 0.f;
#pragma unroll
        for (int c = 0; c < 4; ++c) {
            p = fmaf(xv[c][0], wv[c][0], p); p = fmaf(xv[c][1], wv[c][1], p);
            p = fmaf(xv[c][2], wv[c][2], p); p = fmaf(xv[c][3], wv[c][3], p);
        }
#pragma unroll
        for (int m = 1; m < 64; m <<= 1) p += __shfl_xor(p, m, 64);
#pragma unroll
        for (int c = 0; c < 4; ++c) {
            acc[c][0] = fmaf(p, uv[c][0], acc[c][0]); acc[c][1] = fmaf(p, uv[c][1], acc[c][1]);
            acc[c][2] = fmaf(p, uv[c][2], acc[c][2]); acc[c][3] = fmaf(p, uv[c][3], acc[c][3]);
        }
        node = node * 2 + 1 + ((p > 0.f) ? 1 : 0);
    }
    f32x4* y4 = reinterpret_cast<f32x4*>(y + (size_t)row * FFF_NOUT);
#pragma unroll
    for (int c = 0; c < 4; ++c) y4[c * 64 + lane] = acc[c];
}

extern "C" void kernel_launch(void* const* d_in, const int* in_sizes, int n_in,
                              void* d_out, int out_size, void* d_ws, size_t ws_size,
                              hipStream_t stream) {
    const float* x   = (const float*)d_in[0];
    const float* w1s = (const float*)d_in[1];
    const float* w2s = (const float*)d_in[2];
    float* y = (float*)d_out;

    const size_t wb_bytes = (size_t)SLOTS * sizeof(u16x8);   // 4,192,256
    const size_t need = 2 * wb_bytes;                        // 8,384,512

    if (ws_size >= need) {
        u16x8* w1p = (u16x8*)d_ws;
        u16x8* w2p = (u16x8*)((char*)d_ws + wb_bytes);
        fff_pack_bf16<<<2 * SLOTS / 256, 256, 0, stream>>>(w1s, w2s, w1p, w2p);
        fff_main_bf16<<<FFF_BATCH / 4, 256, 0, stream>>>(x, w1p, w1s, w2p, y);
    } else {
        fff_fused_f32<<<FFF_BATCH / 4, 256, 0, stream>>>(x, w1s, w2s, y);
    }
}

// Round 8
// 106.540 us; speedup vs baseline: 2.9836x; 1.3918x over previous
//
#include <hip/hip_runtime.h>

// FFF tree traversal, round 8: round-7 structure with `#pragma unroll 1` on
// the level loop. The full unroll let the scheduler hoist weight fragments
// across levels -> VGPR pressure -> 64 B/thread scratch spill (the exact
// extra 128 MiB in round 7's WRITE_SIZE). The loop is serially dependent on
// `node`, so unrolling provides no cross-level scheduling freedom anyway.
//
// Layouts (unchanged, proven):
//   x/y : lane owns f32x4 at index c*64+lane (elements 256c+4*lane..+3)
//   w1p/w2p (packed bf16, 128 u16x8 slots/node): slot s=half*64+lane holds
//     elems {512*half+4*lane+k} (k<4) and {512*half+256+4*lane+k} (k>=4).
// Sign safety: |score| < EPS -> recompute dot in fp32 (wave-uniform, rare).

typedef float          f32x4 __attribute__((ext_vector_type(4)));
typedef unsigned short u16x8 __attribute__((ext_vector_type(8)));

#define FFF_BATCH  32768
#define FFF_NIN    1024
#define FFF_NOUT   1024
#define FFF_LEVELS 11
#define FFF_NODES  2047
#define FFF_EPS    0.01f
#define SLOTS      (FFF_NODES * 128)   // u16x8 slots per packed matrix

__device__ __forceinline__ f32x4 ld_nt4f(const f32x4* p) { return __builtin_nontemporal_load(p); }
__device__ __forceinline__ float upbf(unsigned short u) { return __uint_as_float((unsigned)u << 16); }
__device__ __forceinline__ unsigned short tobf(float f) {
    unsigned b = __float_as_uint(f);
    b = (b + 0x7FFFu + ((b >> 16) & 1u)) >> 16;   // round-to-nearest-even
    return (unsigned short)b;
}

// ---- prep: fp32 -> bf16 with the fragment permutation baked in ----
__global__ void fff_pack_bf16(const float* __restrict__ w1, const float* __restrict__ w2,
                              u16x8* __restrict__ o1, u16x8* __restrict__ o2)
{
    int t = blockIdx.x * blockDim.x + threadIdx.x;
    const bool second = t >= SLOTS;
    if (second) t -= SLOTS;
    const float* src = second ? w2 : w1;
    u16x8*       dst = second ? o2 : o1;

    const int node = t >> 7;
    const int s    = t & 127;
    const int half = s >> 6;
    const int lane = s & 63;

    const f32x4* sp = reinterpret_cast<const f32x4*>(src + (size_t)node * FFF_NIN);
    const f32x4 lo = sp[half * 128 + lane];        // elems 512*half + 4*lane ..+3
    const f32x4 hi = sp[half * 128 + 64 + lane];   // elems 512*half + 256 + 4*lane ..+3

    u16x8 o;
#pragma unroll
    for (int k = 0; k < 4; ++k) { o[k] = tobf(lo[k]); o[4 + k] = tobf(hi[k]); }
    dst[t] = o;
}

// ---- main fused kernel: one row per wave, compact rolled level loop ----
__global__ __launch_bounds__(256, 4) void fff_main_bf16(
    const float* __restrict__ x,
    const u16x8* __restrict__ w1p,
    const float* __restrict__ w1f,   // fp32 w1 for the EPS fallback
    const u16x8* __restrict__ w2p,
    float*       __restrict__ y)
{
    const int row  = blockIdx.x * 4 + (threadIdx.x >> 6);
    const int lane = threadIdx.x & 63;

    // coalesced x: xv[c] = elements 256c + 4*lane ..+3
    const f32x4* x4 = reinterpret_cast<const f32x4*>(x + (size_t)row * FFF_NIN);
    f32x4 xv[4];
#pragma unroll
    for (int c = 0; c < 4; ++c) xv[c] = ld_nt4f(&x4[c * 64 + lane]);

    f32x4 acc[4];
#pragma unroll
    for (int c = 0; c < 4; ++c) acc[c] = (f32x4)(0.f);

    int node = 0;

#pragma unroll 1
    for (int l = 0; l < FFF_LEVELS; ++l) {
        const u16x8* w1r = w1p + (size_t)node * 128;
        const u16x8  a0  = w1r[lane];
        const u16x8  a1  = w1r[64 + lane];
        const u16x8* w2r = w2p + (size_t)node * 128;
        const u16x8  b0  = w2r[lane];
        const u16x8  b1  = w2r[64 + lane];

        // dot: slot halves pair with xv[0..3] by construction
        float p = 0.f;
#pragma unroll
        for (int k = 0; k < 4; ++k) {
            p = fmaf(xv[0][k], upbf(a0[k]),     p);
            p = fmaf(xv[1][k], upbf(a0[4 + k]), p);
            p = fmaf(xv[2][k], upbf(a1[k]),     p);
            p = fmaf(xv[3][k], upbf(a1[4 + k]), p);
        }

        // 64-lane butterfly reduce
#pragma unroll
        for (int m = 1; m < 64; m <<= 1) p += __shfl_xor(p, m, 64);

        // rare wave-uniform fp32 recompute for near-zero scores
        if (__builtin_expect(fabsf(p) < FFF_EPS, 0)) {
            const f32x4* w14 = reinterpret_cast<const f32x4*>(w1f + (size_t)node * FFF_NIN);
            float s = 0.f;
#pragma unroll
            for (int c = 0; c < 4; ++c) {
                const f32x4 w = w14[c * 64 + lane];
                s = fmaf(xv[c][0], w[0], s);
                s = fmaf(xv[c][1], w[1], s);
                s = fmaf(xv[c][2], w[2], s);
                s = fmaf(xv[c][3], w[3], s);
            }
#pragma unroll
            for (int m = 1; m < 64; m <<= 1) s += __shfl_xor(s, m, 64);
            p = s;
        }

        // accumulate y, advance node
#pragma unroll
        for (int k = 0; k < 4; ++k) {
            acc[0][k] = fmaf(p, upbf(b0[k]),     acc[0][k]);
            acc[1][k] = fmaf(p, upbf(b0[4 + k]), acc[1][k]);
            acc[2][k] = fmaf(p, upbf(b1[k]),     acc[2][k]);
            acc[3][k] = fmaf(p, upbf(b1[4 + k]), acc[3][k]);
        }
        node = node * 2 + 1 + ((p > 0.f) ? 1 : 0);
    }

    // coalesced y stores (full 128B lines per wave instruction)
    f32x4* y4 = reinterpret_cast<f32x4*>(y + (size_t)row * FFF_NOUT);
#pragma unroll
    for (int c = 0; c < 4; ++c) y4[c * 64 + lane] = acc[c];
}

// ---- safety fallback: proven round-1 fp32 fused kernel ----
__global__ __launch_bounds__(256, 4) void fff_fused_f32(
    const float* __restrict__ x, const float* __restrict__ w1s,
    const float* __restrict__ w2s, float* __restrict__ y)
{
    const int row  = blockIdx.x * 4 + (threadIdx.x >> 6);
    const int lane = threadIdx.x & 63;
    const f32x4* x4 = reinterpret_cast<const f32x4*>(x + (size_t)row * FFF_NIN);
    f32x4 xv[4];
#pragma unroll
    for (int c = 0; c < 4; ++c) xv[c] = x4[c * 64 + lane];
    f32x4 acc[4];
#pragma unroll
    for (int c = 0; c < 4; ++c) acc[c] = (f32x4)(0.f);
    int node = 0;
#pragma unroll 1
    for (int l = 0; l < FFF_LEVELS; ++l) {
        const f32x4* w14 = reinterpret_cast<const f32x4*>(w1s + (size_t)node * FFF_NIN);
        const f32x4* w24 = reinterpret_cast<const f32x4*>(w2s + (size_t)node * FFF_NOUT);
        f32x4 wv[4], uv[4];
#pragma unroll
        for (int c = 0; c < 4; ++c) { wv[c] = w14[c * 64 + lane]; uv[c] = w24[c * 64 + lane]; }
        float p = 0.f;
#pragma unroll
        for (int c = 0; c < 4; ++c) {
            p = fmaf(xv[c][0], wv[c][0], p); p = fmaf(xv[c][1], wv[c][1], p);
            p = fmaf(xv[c][2], wv[c][2], p); p = fmaf(xv[c][3], wv[c][3], p);
        }
#pragma unroll
        for (int m = 1; m < 64; m <<= 1) p += __shfl_xor(p, m, 64);
#pragma unroll
        for (int c = 0; c < 4; ++c) {
            acc[c][0] = fmaf(p, uv[c][0], acc[c][0]); acc[c][1] = fmaf(p, uv[c][1], acc[c][1]);
            acc[c][2] = fmaf(p, uv[c][2], acc[c][2]); acc[c][3] = fmaf(p, uv[c][3], acc[c][3]);
        }
        node = node * 2 + 1 + ((p > 0.f) ? 1 : 0);
    }
    f32x4* y4 = reinterpret_cast<f32x4*>(y + (size_t)row * FFF_NOUT);
#pragma unroll
    for (int c = 0; c < 4; ++c) y4[c * 64 + lane] = acc[c];
}

extern "C" void kernel_launch(void* const* d_in, const int* in_sizes, int n_in,
                              void* d_out, int out_size, void* d_ws, size_t ws_size,
                              hipStream_t stream) {
    const float* x   = (const float*)d_in[0];
    const float* w1s = (const float*)d_in[1];
    const float* w2s = (const float*)d_in[2];
    float* y = (float*)d_out;

    const size_t wb_bytes = (size_t)SLOTS * sizeof(u16x8);   // 4,192,256
    const size_t need = 2 * wb_bytes;                        // 8,384,512

    if (ws_size >= need) {
        u16x8* w1p = (u16x8*)d_ws;
        u16x8* w2p = (u16x8*)((char*)d_ws + wb_bytes);
        fff_pack_bf16<<<2 * SLOTS / 256, 256, 0, stream>>>(w1s, w2s, w1p, w2p);
        fff_main_bf16<<<FFF_BATCH / 4, 256, 0, stream>>>(x, w1p, w1s, w2p, y);
    } else {
        fff_fused_f32<<<FFF_BATCH / 4, 256, 0, stream>>>(x, w1s, w2s, y);
    }
}